// Round 21
// baseline (71.614 us; speedup 1.0000x reference)
//
#include <hip/hip_runtime.h>
#include <hip/hip_fp16.h>
#include <math.h>

#define NDET 512
#define NANG 180
#define NB   8
#define NIMG 512

// ---- ws layout in floats ----
#define WS_CASA 0                      // 180 x {ca,sa} = 360 floats
#define WS_CBT  360                    // cbt[tile][angle] = 256*180 floats
#define WS_FGA  46440                  // region A entries: 180*512*16B = 368,640 floats
#define WS_FGB  (46440 + 368640)       // region B entries: 368,640 floats

typedef _Float16 h2_t __attribute__((ext_vector_type(2)));

__device__ __forceinline__ void gld_lds16(const void* g, void* l) {
    __builtin_amdgcn_global_load_lds((__attribute__((address_space(1))) void*)g,
                                     (__attribute__((address_space(3))) void*)l,
                                     16, 0, 0);
}

__device__ __forceinline__ int hswz(int s) {            // swizzled h-chunk slot
    return (s & 0x78) | ((s ^ (s >> 3)) & 7);
}

// ---------------- kernel 1: Ram-Lak filter + tables + paired-fp16 pack ----------------
__global__ __launch_bounds__(512) void k_filter(const float* __restrict__ x, float* ws) {
    __shared__ float xs[8 * 516];      // 8 padded sinogram rows
    __shared__ float hrs[512];         // swizzled h chunks
    __shared__ float fsm[512 * 8];     // filtered f32 [det][batch]
    const int a    = blockIdx.x;
    const int tid  = threadIdx.x;
    const int lane = tid & 63;
    const int wv   = tid >> 6;         // 0..7 (= batch)

    // stage 8 sinogram rows via global_load_lds
    {
        const float* xr = x + (wv * NANG + a) * NDET;
        gld_lds16(xr + lane * 4,       xs + wv * 516 + lane * 4);
        gld_lds16(xr + 256 + lane * 4, xs + wv * 516 + 256 + lane * 4);
    }
    // h closed form: h[0]=0.25, even->0, odd-> -1/(262144*sin^2(pi*n/512))
    {
        int n = tid;
        float h;
        if (n == 0) h = 0.25f;
        else if ((n & 1) == 0) h = 0.0f;
        else {
            int m = min(n, 512 - n);
            float s = __sinf((float)m * (float)(M_PI / 512.0));
            h = -1.0f / (262144.0f * s * s);
        }
        hrs[hswz(n >> 2) * 4 + (n & 3)] = h;
    }
    // angle tables + per-(tile,angle) window base over EXPANDED (34x34 halo) tile
    if (tid == 0) {
        double th = (double)a * (M_PI / 180.0);
        double sc = 255.5 / sqrt(2.0);
        ws[WS_CASA + 2 * a]     = (float)(cos(th) * sc);
        ws[WS_CASA + 2 * a + 1] = (float)(sin(th) * sc);
    }
    if (tid < 256) {
        double th = (double)a * (M_PI / 180.0);
        double sc = 255.5 / sqrt(2.0);
        const float cad = (float)(cos(th) * sc), sad = (float)(sin(th) * sc);
        const int bx = tid & 15, by = tid >> 4;    // tile id
        const float x0 = -1.f + (float)(bx * 32 - 1)  * (2.f / 511.f);
        const float x1 = -1.f + (float)(bx * 32 + 32) * (2.f / 511.f);
        const float y0 = -1.f + (float)(by * 32 - 1)  * (2.f / 511.f);
        const float y1 = -1.f + (float)(by * 32 + 32) * (2.f / 511.f);
        float u00 = fmaf(x0, cad, fmaf(y0, sad, 255.5f));
        float u01 = fmaf(x1, cad, fmaf(y0, sad, 255.5f));
        float u10 = fmaf(x0, cad, fmaf(y1, sad, 255.5f));
        float u11 = fmaf(x1, cad, fmaf(y1, sad, 255.5f));
        float umin = fminf(fminf(u00, u01), fminf(u10, u11));
        int d0 = (int)floorf(umin);                // 34-entry window
        d0 = max(0, min(NDET - 35, d0));
        ws[WS_CBT + tid * 180 + a] = 255.5f - (float)d0;
    }
    __syncthreads();     // drains global_load_lds (vmcnt) + LDS writes

    {
        const int b  = lane & 7;
        const int t  = lane >> 3;
        const int n0 = wv * 64 + t * 8;
        const int q  = n0 >> 2;
        const float* xrow = xs + b * 516;

        float acc[8] = {0, 0, 0, 0, 0, 0, 0, 0};
        float win[12];
        {
            int s2 = (-q - 2) & 127;
            int s1 = (-q - 1) & 127;
            float4 h2 = *(const float4*)(hrs + hswz(s2) * 4);
            float4 h1 = *(const float4*)(hrs + hswz(s1) * 4);
            win[0] = h2.x; win[1] = h2.y; win[2]  = h2.z; win[3]  = h2.w;
            win[4] = h1.x; win[5] = h1.y; win[6]  = h1.z; win[7]  = h1.w;
        }
        #pragma unroll 4
        for (int c = 0; c < 128; ++c) {
            int s = (c - q) & 127;
            float4 hc = *(const float4*)(hrs + hswz(s) * 4);
            win[8] = hc.x; win[9] = hc.y; win[10] = hc.z; win[11] = hc.w;
            float4 xv = *(const float4*)(xrow + c * 4);
            float xa[4] = {xv.x, xv.y, xv.z, xv.w};
            #pragma unroll
            for (int k = 0; k < 8; ++k)
                #pragma unroll
                for (int j = 0; j < 4; ++j)
                    acc[k] = fmaf(xa[j], win[8 + j - k], acc[k]);
            #pragma unroll
            for (int i2 = 0; i2 < 8; ++i2) win[i2] = win[i2 + 4];
        }
        #pragma unroll
        for (int k = 0; k < 8; ++k)
            fsm[(n0 + k) * 8 + b] = acc[k];
    }
    __syncthreads();
    {
        const int d  = tid;
        const int d1 = min(d + 1, NDET - 1);
        const float* A  = fsm + d * 8;
        const float* Bv = fsm + d1 * 8;
        uint4 eA, eB;
        unsigned wds[8];
        #pragma unroll
        for (int b = 0; b < 8; ++b) {
            __half2 h;
            h.x = __float2half(A[b]);
            h.y = __float2half(Bv[b]);
            wds[b] = __builtin_bit_cast(unsigned, h);
        }
        eA.x = wds[0]; eA.y = wds[1]; eA.z = wds[2]; eA.w = wds[3];
        eB.x = wds[4]; eB.y = wds[5]; eB.z = wds[6]; eB.w = wds[7];
        *(uint4*)((char*)(ws + WS_FGA) + (a * NDET + d) * 16) = eA;
        *(uint4*)((char*)(ws + WS_FGB) + (a * NDET + d) * 16) = eB;
    }
}

// ---------------- kernel 2: backprojection + fused blur (split gather) ----------------
// Region A (batches 0-3): LDS, all 180 angles staged once (97,920 B, 1 barrier).
// Region B (batches 4-7): direct global gather (VMEM/L1 pipe, concurrent w/ LDS).
#define WWE  34

__global__ __launch_bounds__(1024, 4) void k_bp(float* ws, float* __restrict__ out) {
    __shared__ uint4 winA[NANG * WWE];   // 97,920 B (blur grid aliases after comp)
    __shared__ float casal[2 * NANG];
    __shared__ float cbl[NANG];
    const int tid  = threadIdx.x;
    const int wv   = tid >> 6, lane = tid & 63;
    const int tile = blockIdx.x;
    const int bx   = tile & 15, by = tile >> 4;

    // interior pixel (8x8 subtile mapping, always in-image)
    const int iy1 = (wv >> 2) * 8 + (lane >> 3);   // 0..31
    const int ix1 = (wv & 3) * 8 + (lane & 7);     // 0..31
    const int lx1 = ix1 + 1, ly1 = iy1 + 1;
    const float xf1 = -1.0f + (float)(bx * 32 + ix1) * (2.0f / 511.0f);
    const float yf1 = -1.0f + (float)(by * 32 + iy1) * (2.0f / 511.0f);

    // ring pixel (tid < 132): border of the 34x34 grid
    const bool has2 = (tid < 132);
    int lx2, ly2;
    {
        const int i = tid;
        if (i < 34)       { lx2 = i;        ly2 = 0;       }
        else if (i < 68)  { lx2 = i - 34;   ly2 = 33;      }
        else if (i < 100) { lx2 = 0;        ly2 = i - 67;  }
        else              { lx2 = 33;       ly2 = i - 99;  }
    }
    const int gx2 = bx * 32 - 1 + lx2, gy2 = by * 32 - 1 + ly2;
    const bool in2 = has2 && (gx2 >= 0) && (gx2 < NIMG) && (gy2 >= 0) && (gy2 < NIMG);
    const float xf2 = -1.0f + (float)gx2 * (2.0f / 511.0f);
    const float yf2 = -1.0f + (float)gy2 * (2.0f / 511.0f);

    const char*  __restrict__ fga  = (const char*)(ws + WS_FGA);
    const char*  __restrict__ fgb  = (const char*)(ws + WS_FGB);
    const float* __restrict__ cbtg = ws + WS_CBT + tile * 180;

    // stage region A for all 180 angles (d0 from global cbt, no LDS dependency)
    #pragma unroll
    for (int r = 0; r < 6; ++r) {
        int c = r * 1024 + tid;
        if (c < NANG * WWE) {
            int a = c / WWE;
            int o = c - a * WWE;
            int d0 = (int)(255.5f - cbtg[a]);
            gld_lds16(fga + (a * NDET + d0 + o) * 16, winA + c);
        }
    }
    if (tid < NANG) {
        cbl[tid] = cbtg[tid];
        casal[2 * tid]     = ws[WS_CASA + 2 * tid];
        casal[2 * tid + 1] = ws[WS_CASA + 2 * tid + 1];
    }
    __syncthreads();     // drains stage + table writes

    float acc1[8] = {0, 0, 0, 0, 0, 0, 0, 0};
    float acc2[8] = {0, 0, 0, 0, 0, 0, 0, 0};
    auto comp = [&](float xf, float yf, float* acc) {
        #pragma unroll 4
        for (int al = 0; al < NANG; ++al) {
            const float ca = casal[2 * al], sa = casal[2 * al + 1];
            const float cb = cbl[al];
            float v = fmaf(xf, ca, fmaf(yf, sa, cb));
            v = __builtin_amdgcn_fmed3f(v, 0.0f, 33.99996948f);
            float fj = floorf(v);
            float w  = v - fj;
            int  j0  = (int)fj;
            const int d0 = (int)(255.5f - cb);
            uint4 dA = winA[al * WWE + j0];
            uint4 dB = *(const uint4*)(fgb + (al * NDET + d0 + j0) * 16);
            h2_t wp = __builtin_bit_cast(h2_t, __builtin_amdgcn_cvt_pkrtz(1.0f - w, w));
            acc[0] = __builtin_amdgcn_fdot2(__builtin_bit_cast(h2_t, dA.x), wp, acc[0], false);
            acc[1] = __builtin_amdgcn_fdot2(__builtin_bit_cast(h2_t, dA.y), wp, acc[1], false);
            acc[2] = __builtin_amdgcn_fdot2(__builtin_bit_cast(h2_t, dA.z), wp, acc[2], false);
            acc[3] = __builtin_amdgcn_fdot2(__builtin_bit_cast(h2_t, dA.w), wp, acc[3], false);
            acc[4] = __builtin_amdgcn_fdot2(__builtin_bit_cast(h2_t, dB.x), wp, acc[4], false);
            acc[5] = __builtin_amdgcn_fdot2(__builtin_bit_cast(h2_t, dB.y), wp, acc[5], false);
            acc[6] = __builtin_amdgcn_fdot2(__builtin_bit_cast(h2_t, dB.z), wp, acc[6], false);
            acc[7] = __builtin_amdgcn_fdot2(__builtin_bit_cast(h2_t, dB.w), wp, acc[7], false);
        }
    };

    comp(xf1, yf1, acc1);
    if (has2) comp(xf2, yf2, acc2);

    // ---- fused 3x3 gaussian blur + clip (grid aliases winA) ----
    const float scale = (float)((2.0 / 512.0) * M_PI / 180.0);
    const float KA = 0.10650697891920077f;   // e^-2 / (1+2e^-2)
    const float KB = 0.78698604216159850f;   // 1 / (1+2e^-2)
    float* grid = (float*)&winA[0];          // 34 x 35 floats
    const int ixl = (tid & 31) + 1, iyl = (tid >> 5) + 1;
    const int ogx = bx * 32 + (tid & 31), ogy = by * 32 + (tid >> 5);

    #pragma unroll
    for (int b = 0; b < 8; ++b) {
        __syncthreads();                     // comp / previous blur reads done
        grid[ly1 * 35 + lx1] = acc1[b] * scale;
        if (has2) grid[ly2 * 35 + lx2] = in2 ? acc2[b] * scale : 0.0f;
        __syncthreads();
        const float* g0 = grid + (iyl - 1) * 35 + ixl;
        const float* g1 = grid + iyl * 35 + ixl;
        const float* g2 = grid + (iyl + 1) * 35 + ixl;
        float rowm = KA * (g0[-1] + g0[1]) + KB * g0[0];
        float row0 = KA * (g1[-1] + g1[1]) + KB * g1[0];
        float rowp = KA * (g2[-1] + g2[1]) + KB * g2[0];
        float v = KA * (rowm + rowp) + KB * row0;
        v = fminf(fmaxf(v, -1.0f), 1.0f);
        out[b * (NIMG * NIMG) + ogy * NIMG + ogx] = v;
    }
}

extern "C" void kernel_launch(void* const* d_in, const int* in_sizes, int n_in,
                              void* d_out, int out_size, void* d_ws, size_t ws_size,
                              hipStream_t stream) {
    const float* x = (const float*)d_in[0];
    float* out = (float*)d_out;
    float* ws  = (float*)d_ws;

    k_filter<<<NANG, 512, 0, stream>>>(x, ws);
    k_bp<<<256, 1024, 0, stream>>>(ws, out);
}

// Round 22
// 62.707 us; speedup vs baseline: 1.1421x; 1.1421x over previous
//
#include <hip/hip_runtime.h>
#include <hip/hip_fp16.h>
#include <math.h>

#define NDET 512
#define NANG 180
#define NB   8
#define NIMG 512

// ---- ws layout in floats ----
#define WS_CASA 0                      // 180 x {ca,sa} = 360 floats
#define WS_CBT  360                    // cbt[tile][angle] = 256*180 floats
#define WS_FGA  46440                  // region A entries: 180*512*16B = 368,640 floats
#define WS_FGB  (46440 + 368640)       // region B entries: 368,640 floats

typedef _Float16 h2_t __attribute__((ext_vector_type(2)));

__device__ __forceinline__ void gld_lds16(const void* g, void* l) {
    __builtin_amdgcn_global_load_lds((__attribute__((address_space(1))) void*)g,
                                     (__attribute__((address_space(3))) void*)l,
                                     16, 0, 0);
}

__device__ __forceinline__ int hswz(int s) {            // swizzled h-chunk slot
    return (s & 0x78) | ((s ^ (s >> 3)) & 7);
}

// ---------------- kernel 1: Ram-Lak filter + tables + paired-fp16 pack ----------------
__global__ __launch_bounds__(512) void k_filter(const float* __restrict__ x, float* ws) {
    __shared__ float xs[8 * 516];      // 8 padded sinogram rows
    __shared__ float hrs[512];         // swizzled h chunks
    __shared__ float fsm[512 * 8];     // filtered f32 [det][batch]
    const int a    = blockIdx.x;
    const int tid  = threadIdx.x;
    const int lane = tid & 63;
    const int wv   = tid >> 6;         // 0..7 (= batch)

    // stage 8 sinogram rows via global_load_lds
    {
        const float* xr = x + (wv * NANG + a) * NDET;
        gld_lds16(xr + lane * 4,       xs + wv * 516 + lane * 4);
        gld_lds16(xr + 256 + lane * 4, xs + wv * 516 + 256 + lane * 4);
    }
    // h closed form: h[0]=0.25, even->0, odd-> -1/(262144*sin^2(pi*n/512))
    {
        int n = tid;
        float h;
        if (n == 0) h = 0.25f;
        else if ((n & 1) == 0) h = 0.0f;
        else {
            int m = min(n, 512 - n);
            float s = __sinf((float)m * (float)(M_PI / 512.0));
            h = -1.0f / (262144.0f * s * s);
        }
        hrs[hswz(n >> 2) * 4 + (n & 3)] = h;
    }
    // angle tables + per-(tile,angle) window base over EXPANDED (34x34 halo) tile
    if (tid == 0) {
        double th = (double)a * (M_PI / 180.0);
        double sc = 255.5 / sqrt(2.0);
        ws[WS_CASA + 2 * a]     = (float)(cos(th) * sc);
        ws[WS_CASA + 2 * a + 1] = (float)(sin(th) * sc);
    }
    if (tid < 256) {
        double th = (double)a * (M_PI / 180.0);
        double sc = 255.5 / sqrt(2.0);
        const float cad = (float)(cos(th) * sc), sad = (float)(sin(th) * sc);
        const int bx = tid & 15, by = tid >> 4;    // tile id
        const float x0 = -1.f + (float)(bx * 32 - 1)  * (2.f / 511.f);
        const float x1 = -1.f + (float)(bx * 32 + 32) * (2.f / 511.f);
        const float y0 = -1.f + (float)(by * 32 - 1)  * (2.f / 511.f);
        const float y1 = -1.f + (float)(by * 32 + 32) * (2.f / 511.f);
        float u00 = fmaf(x0, cad, fmaf(y0, sad, 255.5f));
        float u01 = fmaf(x1, cad, fmaf(y0, sad, 255.5f));
        float u10 = fmaf(x0, cad, fmaf(y1, sad, 255.5f));
        float u11 = fmaf(x1, cad, fmaf(y1, sad, 255.5f));
        float umin = fminf(fminf(u00, u01), fminf(u10, u11));
        int d0 = (int)floorf(umin);                // 34-entry window
        d0 = max(0, min(NDET - 35, d0));
        ws[WS_CBT + tid * 180 + a] = 255.5f - (float)d0;
    }
    __syncthreads();     // drains global_load_lds (vmcnt) + LDS writes

    {
        const int b  = lane & 7;
        const int t  = lane >> 3;
        const int n0 = wv * 64 + t * 8;
        const int q  = n0 >> 2;
        const float* xrow = xs + b * 516;

        float acc[8] = {0, 0, 0, 0, 0, 0, 0, 0};
        float win[12];
        {
            int s2 = (-q - 2) & 127;
            int s1 = (-q - 1) & 127;
            float4 h2 = *(const float4*)(hrs + hswz(s2) * 4);
            float4 h1 = *(const float4*)(hrs + hswz(s1) * 4);
            win[0] = h2.x; win[1] = h2.y; win[2]  = h2.z; win[3]  = h2.w;
            win[4] = h1.x; win[5] = h1.y; win[6]  = h1.z; win[7]  = h1.w;
        }
        #pragma unroll 4
        for (int c = 0; c < 128; ++c) {
            int s = (c - q) & 127;
            float4 hc = *(const float4*)(hrs + hswz(s) * 4);
            win[8] = hc.x; win[9] = hc.y; win[10] = hc.z; win[11] = hc.w;
            float4 xv = *(const float4*)(xrow + c * 4);
            float xa[4] = {xv.x, xv.y, xv.z, xv.w};
            #pragma unroll
            for (int k = 0; k < 8; ++k)
                #pragma unroll
                for (int j = 0; j < 4; ++j)
                    acc[k] = fmaf(xa[j], win[8 + j - k], acc[k]);
            #pragma unroll
            for (int i2 = 0; i2 < 8; ++i2) win[i2] = win[i2 + 4];
        }
        #pragma unroll
        for (int k = 0; k < 8; ++k)
            fsm[(n0 + k) * 8 + b] = acc[k];
    }
    __syncthreads();
    {
        const int d  = tid;
        const int d1 = min(d + 1, NDET - 1);
        const float* A  = fsm + d * 8;
        const float* Bv = fsm + d1 * 8;
        uint4 eA, eB;
        unsigned wds[8];
        #pragma unroll
        for (int b = 0; b < 8; ++b) {
            __half2 h;
            h.x = __float2half(A[b]);
            h.y = __float2half(Bv[b]);
            wds[b] = __builtin_bit_cast(unsigned, h);
        }
        eA.x = wds[0]; eA.y = wds[1]; eA.z = wds[2]; eA.w = wds[3];
        eB.x = wds[4]; eB.y = wds[5]; eB.z = wds[6]; eB.w = wds[7];
        *(uint4*)((char*)(ws + WS_FGA) + (a * NDET + d) * 16) = eA;
        *(uint4*)((char*)(ws + WS_FGB) + (a * NDET + d) * 16) = eB;
    }
}

// ---------------- kernel 2: backprojection + fused blur (34x34 halo tiles) ----------------
// Interior 32x32 px: 8x8-subtile wave mapping (j0 spread <=9 -> ~2-way, free).
// Halo ring (132 px) on tids 0..131 as a second accumulator.
#define WWE  34
#define CHA  60
#define ECH  (CHA * WWE)               // 2040 entries per chunk per region

__global__ __launch_bounds__(1024, 4) void k_bp(float* ws, float* __restrict__ out) {
    __shared__ uint4 win4[2][2 * ECH];   // 130,560 B (blur grids alias this after comp)
    __shared__ float casal[2 * NANG];
    __shared__ float cbl[NANG];
    const int tid  = threadIdx.x;
    const int wv   = tid >> 6, lane = tid & 63;
    const int tile = blockIdx.x;
    const int bx   = tile & 15, by = tile >> 4;

    // interior pixel (8x8 subtile mapping, always in-image)
    const int iy1 = (wv >> 2) * 8 + (lane >> 3);   // 0..31
    const int ix1 = (wv & 3) * 8 + (lane & 7);     // 0..31
    const int lx1 = ix1 + 1, ly1 = iy1 + 1;        // local 34x34 coords
    const float xf1 = -1.0f + (float)(bx * 32 + ix1) * (2.0f / 511.0f);
    const float yf1 = -1.0f + (float)(by * 32 + iy1) * (2.0f / 511.0f);

    // ring pixel (tid < 132): border of the 34x34 grid
    const bool has2 = (tid < 132);
    int lx2, ly2;
    {
        const int i = tid;
        if (i < 34)       { lx2 = i;        ly2 = 0;       }
        else if (i < 68)  { lx2 = i - 34;   ly2 = 33;      }
        else if (i < 100) { lx2 = 0;        ly2 = i - 67;  }   // 1..32
        else              { lx2 = 33;       ly2 = i - 99;  }   // 1..32
    }
    const int gx2 = bx * 32 - 1 + lx2, gy2 = by * 32 - 1 + ly2;
    const bool in2 = has2 && (gx2 >= 0) && (gx2 < NIMG) && (gy2 >= 0) && (gy2 < NIMG);
    const float xf2 = -1.0f + (float)gx2 * (2.0f / 511.0f);
    const float yf2 = -1.0f + (float)gy2 * (2.0f / 511.0f);

    const char* __restrict__ fga = (const char*)(ws + WS_FGA);
    const char* __restrict__ fgb = (const char*)(ws + WS_FGB);

    if (tid < NANG) {
        cbl[tid] = ws[WS_CBT + tile * 180 + tid];
        casal[2 * tid]     = ws[WS_CASA + 2 * tid];
        casal[2 * tid + 1] = ws[WS_CASA + 2 * tid + 1];
    }
    __syncthreads();

    auto stageq = [&](int buf, int ch) {
        #pragma unroll
        for (int r = 0; r < 4; ++r) {
            int c = r * 1024 + tid;
            if (c < 2 * ECH) {
                int reg = c / ECH;
                int e   = c - reg * ECH;
                int a   = e / WWE;
                int o   = e - a * WWE;
                int ag  = ch * CHA + a;
                int d0  = (int)(255.5f - cbl[ag]);
                const char* g = (reg ? fgb : fga) + (ag * NDET + d0 + o) * 16;
                gld_lds16(g, (char*)(&win4[buf][0]) + c * 16);
            }
        }
    };

    float acc1[8] = {0, 0, 0, 0, 0, 0, 0, 0};
    float acc2[8] = {0, 0, 0, 0, 0, 0, 0, 0};
    auto comp = [&](int buf, int ch, float xf, float yf, float* acc) {
        #pragma unroll 4
        for (int al = 0; al < CHA; ++al) {
            const int ag = ch * CHA + al;
            const float ca = casal[2 * ag], sa = casal[2 * ag + 1];
            const float cb = cbl[ag];
            float v = fmaf(xf, ca, fmaf(yf, sa, cb));
            v = __builtin_amdgcn_fmed3f(v, 0.0f, 33.99996948f);
            float fj = floorf(v);
            float w  = v - fj;
            int  j0  = (int)fj;
            uint4 dA = win4[buf][al * WWE + j0];
            uint4 dB = win4[buf][ECH + al * WWE + j0];
            h2_t wp = __builtin_bit_cast(h2_t, __builtin_amdgcn_cvt_pkrtz(1.0f - w, w));
            acc[0] = __builtin_amdgcn_fdot2(__builtin_bit_cast(h2_t, dA.x), wp, acc[0], false);
            acc[1] = __builtin_amdgcn_fdot2(__builtin_bit_cast(h2_t, dA.y), wp, acc[1], false);
            acc[2] = __builtin_amdgcn_fdot2(__builtin_bit_cast(h2_t, dA.z), wp, acc[2], false);
            acc[3] = __builtin_amdgcn_fdot2(__builtin_bit_cast(h2_t, dA.w), wp, acc[3], false);
            acc[4] = __builtin_amdgcn_fdot2(__builtin_bit_cast(h2_t, dB.x), wp, acc[4], false);
            acc[5] = __builtin_amdgcn_fdot2(__builtin_bit_cast(h2_t, dB.y), wp, acc[5], false);
            acc[6] = __builtin_amdgcn_fdot2(__builtin_bit_cast(h2_t, dB.z), wp, acc[6], false);
            acc[7] = __builtin_amdgcn_fdot2(__builtin_bit_cast(h2_t, dB.w), wp, acc[7], false);
        }
    };

    stageq(0, 0); __syncthreads();
    stageq(1, 1);
    comp(0, 0, xf1, yf1, acc1);
    if (has2) comp(0, 0, xf2, yf2, acc2);
    __syncthreads();
    stageq(0, 2);
    comp(1, 1, xf1, yf1, acc1);
    if (has2) comp(1, 1, xf2, yf2, acc2);
    __syncthreads();
    comp(0, 2, xf1, yf1, acc1);
    if (has2) comp(0, 2, xf2, yf2, acc2);

    // ---- fused 3x3 gaussian blur + clip (double-buffered grid aliases win4) ----
    const float scale = (float)((2.0 / 512.0) * M_PI / 180.0);
    const float KA = 0.10650697891920077f;   // e^-2 / (1+2e^-2)
    const float KB = 0.78698604216159850f;   // 1 / (1+2e^-2)
    float* grid0 = (float*)&win4[0][0];      // 34 x 35 floats
    float* grid1 = grid0 + 34 * 35;          // second buffer
    const int ixl = (tid & 31) + 1, iyl = (tid >> 5) + 1;
    const int ogx = bx * 32 + (tid & 31), ogy = by * 32 + (tid >> 5);

    __syncthreads();                         // all comp LDS reads done before overwrite
    #pragma unroll
    for (int b = 0; b < 8; ++b) {
        float* grid = (b & 1) ? grid1 : grid0;
        grid[ly1 * 35 + lx1] = acc1[b] * scale;
        if (has2) grid[ly2 * 35 + lx2] = in2 ? acc2[b] * scale : 0.0f;
        __syncthreads();                     // write -> read separation (dbuf covers W/R of next iter)
        const float* g0 = grid + (iyl - 1) * 35 + ixl;
        const float* g1 = grid + iyl * 35 + ixl;
        const float* g2 = grid + (iyl + 1) * 35 + ixl;
        float rowm = KA * (g0[-1] + g0[1]) + KB * g0[0];
        float row0 = KA * (g1[-1] + g1[1]) + KB * g1[0];
        float rowp = KA * (g2[-1] + g2[1]) + KB * g2[0];
        float v = KA * (rowm + rowp) + KB * row0;
        v = fminf(fmaxf(v, -1.0f), 1.0f);
        out[b * (NIMG * NIMG) + ogy * NIMG + ogx] = v;
    }
}

extern "C" void kernel_launch(void* const* d_in, const int* in_sizes, int n_in,
                              void* d_out, int out_size, void* d_ws, size_t ws_size,
                              hipStream_t stream) {
    const float* x = (const float*)d_in[0];
    float* out = (float*)d_out;
    float* ws  = (float*)d_ws;

    k_filter<<<NANG, 512, 0, stream>>>(x, ws);
    k_bp<<<256, 1024, 0, stream>>>(ws, out);
}